// Round 16
// baseline (71.556 us; speedup 1.0000x reference)
//
#include <hip/hip_runtime.h>
#include <stdint.h>

// Block-factorized depthwise 7x7 conv, per-(n,c,8x8-block) filters.
// feat: [N=2, C=128, H=256, W=256] f32 (NCHW)
// filters_lr: [N, C*49, 32, 32] f32 ; weight[n,hb,wb,c,t] = filt[n, c*49+t, hb, wb]
// out[n,c,h,w] = sum_t feat[n,c,h+dh-3,w+dw-3] * weight[n,h/8,w/8,c,t], t=dh*7+dw
//
// MULTI-TILE WAVES + CROSS-TILE WEIGHT PREFETCH.
// One 64-thread wave-block processes 4 consecutive hb tiles of one (n,c).
// Rounds 9-12 established: per-wave cold-start drain (~12k of 17k cyc
// lifetime) is the invariant cost; waves stall in correlated epochs so
// resident waves don't cover each other (3.25 TB/s effective vs 6.3 proven).
// Here each tile's weights are staged into a double-buffered LDS slab ONE
// TILE AHEAD (r12's proven 7x global_load_lds scatter; ~4.5k cyc of FMA hides
// the ~900cyc latency). Loop-top s_waitcnt vmcnt(0) costs only the previous
// tile's store tail. Rows stay clamped reg loads (compiler-counted vmcnt).
// Rolled tile loop keeps code ~15KB (I-cache). launch_bounds(64,3): VGPR cap
// ~170 (live ~159: rows 56 + wt 49 + acc 32 + win/addr), 12 waves/CU class.
// Grid 2048 = exactly 8 blocks/CU resident, zero tail.

#define SLABF 1568   // floats per weight slab (49 taps * 32 wb)

typedef const uint32_t __attribute__((address_space(1))) guint;
typedef uint32_t __attribute__((address_space(3))) luint;

__global__ __launch_bounds__(64, 3)
void block_fac_kernel(const float* __restrict__ feat,
                      const float* __restrict__ filt,
                      float* __restrict__ out) {
    __shared__ float s_w[2 * SLABF];      // 12544 B, ping-pong slabs

    const int bid = blockIdx.x;           // (n*128+c)*8 + q
    const int q   = bid & 7;              // hb quartet (tiles hb = 4q..4q+3)
    const int c   = (bid >> 3) & 127;
    const int n   = bid >> 10;
    const int lane = threadIdx.x;         // 0..63

    const int c0 = lane << 2;             // output col base (0..252)
    const int wb = lane >> 1;             // weight block col (0..31)

    const float* fbase = feat + (size_t)(n * 128 + c) * 65536;
    const float* wtap0 = filt + (size_t)((n * 128 + c) * 49) * 1024 + q * 128;

    // ---- prologue: stage tile-0 weights into slab 0 (r12's scatter scheme:
    // flat 16B chunk f = i*64+lane ; tap = f>>3 ; chunk = f&7; LDS linear dest)
    #pragma unroll
    for (int i = 0; i < 7; ++i) {
        if (i < 6 || lane < 8) {
            int f = (i << 6) | lane;
            const float* gp = wtap0 + (size_t)(f >> 3) * 1024 + (f & 7) * 4;
            __builtin_amdgcn_global_load_lds((guint*)gp, (luint*)(s_w + i * 256), 16, 0, 0);
        }
    }

    const int addrL = ((lane - 1) & 63) << 2;   // bpermute: pull from lane-1
    const int addrR = ((lane + 1) & 63) << 2;   // pull from lane+1
    const bool l0  = (lane == 0);
    const bool l63 = (lane == 63);

    #pragma unroll 1
    for (int t = 0; t < 4; ++t) {         // 4 hb tiles per wave
        // drain: slab for THIS tile (issued a full tile ago) + prev stores' tail
        asm volatile("s_waitcnt vmcnt(0)" ::: "memory");
        __builtin_amdgcn_sched_barrier(0);

        // ---- hoist this tile's weights LDS->reg (b32, bank=wb, pair-broadcast)
        const float* ws = s_w + ((t & 1) ? SLABF : 0) + wb;
        float wt[49];
        #pragma unroll
        for (int k = 0; k < 49; ++k) wt[k] = ws[k * 32];

        const int H0 = (q * 4 + t) * 8;   // first output row of this tile

        // ---- 14 input rows: own float4, clamped address -> unconditional
        float4 row[14];
        #pragma unroll
        for (int r = 0; r < 14; ++r) {
            int gr  = H0 - 3 + r;
            int grc = gr < 0 ? 0 : (gr > 255 ? 255 : gr);
            row[r] = *(const float4*)(fbase + (size_t)grc * 256 + c0);
        }

        // ---- prefetch NEXT tile's weights into the other slab (hidden under FMAs)
        if (t < 3) {
            const float* wtap = wtap0 + (t + 1) * 32;
            float* dst = s_w + ((t & 1) ? 0 : SLABF);
            #pragma unroll
            for (int i = 0; i < 7; ++i) {
                if (i < 6 || lane < 8) {
                    int f = (i << 6) | lane;
                    const float* gp = wtap + (size_t)(f >> 3) * 1024 + (f & 7) * 4;
                    __builtin_amdgcn_global_load_lds((guint*)gp, (luint*)(dst + i * 256), 16, 0, 0);
                }
            }
        }

        float acc[8][4] = {};

        #pragma unroll
        for (int jj = 0; jj < 14; ++jj) { // input row H0-3+jj ; out row a: dh=jj-a
            const int gr = H0 - 3 + jj;   // wave-uniform validity
            float4 f = row[jj];
            if (gr < 0 || gr > 255) f = make_float4(0.f, 0.f, 0.f, 0.f);

            float L1 = __int_as_float(__builtin_amdgcn_ds_bpermute(addrL, __float_as_int(f.y)));
            float L2 = __int_as_float(__builtin_amdgcn_ds_bpermute(addrL, __float_as_int(f.z)));
            float L3 = __int_as_float(__builtin_amdgcn_ds_bpermute(addrL, __float_as_int(f.w)));
            float R0 = __int_as_float(__builtin_amdgcn_ds_bpermute(addrR, __float_as_int(f.x)));
            float R1 = __int_as_float(__builtin_amdgcn_ds_bpermute(addrR, __float_as_int(f.y)));
            float R2 = __int_as_float(__builtin_amdgcn_ds_bpermute(addrR, __float_as_int(f.z)));
            if (l0)  { L1 = 0.f; L2 = 0.f; L3 = 0.f; }   // cols -3..-1
            if (l63) { R0 = 0.f; R1 = 0.f; R2 = 0.f; }   // cols 256..258

            // win[k] = feat col c0 + k - 4 (k=1..10 used)
            float win[12] = {0.f, L1, L2, L3,
                             f.x, f.y, f.z, f.w,
                             R0, R1, R2, 0.f};
            #pragma unroll
            for (int a = 0; a < 8; ++a) {
                int dh = jj - a;
                if (dh >= 0 && dh <= 6) {
                    #pragma unroll
                    for (int dw = 0; dw < 7; ++dw) {
                        float wv = wt[dh * 7 + dw];
                        #pragma unroll
                        for (int i = 0; i < 4; ++i)
                            acc[a][i] += win[i + dw + 1] * wv;   // col c0+i+dw-3
                    }
                }
            }
        }

        float* obase = out + (size_t)((n * 128 + c) * 256 + H0) * 256 + c0;
        #pragma unroll
        for (int a = 0; a < 8; ++a)
            *(float4*)(obase + (size_t)(a * 256)) =
                make_float4(acc[a][0], acc[a][1], acc[a][2], acc[a][3]);
    }
}

extern "C" void kernel_launch(void* const* d_in, const int* in_sizes, int n_in,
                              void* d_out, int out_size, void* d_ws, size_t ws_size,
                              hipStream_t stream) {
    const float* feat = (const float*)d_in[0];
    const float* filt = (const float*)d_in[1];
    float* out = (float*)d_out;
    dim3 grid(2 * 128 * 8);               // 2048 wave-blocks x 4 tiles
    dim3 block(64);
    hipLaunchKernelGGL(block_fac_kernel, grid, block, 0, stream, feat, filt, out);
}

// Round 17
// 61.054 us; speedup vs baseline: 1.1720x; 1.1720x over previous
//
#include <hip/hip_runtime.h>
#include <stdint.h>

// Block-factorized depthwise 7x7 conv, per-(n,c,8x8-block) filters.
// feat: [N=2, C=128, H=256, W=256] f32 (NCHW)
// filters_lr: [N, C*49, 32, 32] f32 ; weight[n,hb,wb,c,t] = filt[n, c*49+t, hb, wb]
// out[n,c,h,w] = sum_t feat[n,c,h+dh-3,w+dw-3] * weight[n,h/8,w/8,c,t], t=dh*7+dw
//
// r12 VERBATIM (the clean 40.6us vehicle: VGPR 128, zero spill, conflicts 0)
// + exactly ONE change: nontemporal output stores (native ext_vector_type;
// HIP float4 class is rejected by the builtin). Working set 179MB < 256MB L3;
// theory: the allocating 64MB write stream evicts inputs from L3 each pass
// (FETCH 63MB/pass). nt stores bypass -> inputs stay L3-resident.
// This A/B was attempted r13 (compile error), r14/r15 (codegen spills);
// this is the first clean measurement.

#define SLABF 1568   // floats per wave weight slab (49 taps * 32 wb)

typedef const uint32_t __attribute__((address_space(1))) guint;
typedef uint32_t __attribute__((address_space(3))) luint;
typedef float __attribute__((ext_vector_type(4))) fx4;

__global__ __launch_bounds__(256, 1)
void block_fac_kernel(const float* __restrict__ feat,
                      const float* __restrict__ filt,
                      float* __restrict__ out) {
    __shared__ float s_w[4 * SLABF];      // 25088 B, one slab per wave

    const int wave = threadIdx.x >> 6;
    const int lane = threadIdx.x & 63;
    const int wid  = (blockIdx.x << 2) | wave;   // global wave id
    const int hb   = wid & 31;
    const int c    = (wid >> 5) & 127;
    const int n    = wid >> 12;

    const int c0 = lane << 2;             // output col base (0..252)
    const int wb = lane >> 1;             // weight block col (0..31)
    const int H0 = hb * 8;                // first output row

    const float* fbase = feat + (size_t)(n * 128 + c) * (256 * 256);
    const float* wtap  = filt + (size_t)((n * 128 + c) * 49) * 1024 + hb * 32;
    float* slab = s_w + wave * SLABF;

    // ---- stage the 6272B weight block into LDS: 7 fire-and-forget gathers.
    // flat 16B-chunk f = i*64+lane ; tap t = f>>3 ; chunk = f&7.
    #pragma unroll
    for (int i = 0; i < 7; ++i) {
        if (i < 6 || lane < 8) {          // tail instr: only tap 48 (8 chunks)
            int f = (i << 6) | lane;
            const float* gp = wtap + (size_t)(f >> 3) * 1024 + (f & 7) * 4;
            float* lp = slab + i * 256;   // wave-uniform base; HW adds lane*16
            __builtin_amdgcn_global_load_lds((guint*)gp, (luint*)lp, 16, 0, 0);
        }
    }

    // ---- 14 input rows: own float4, clamped address -> unconditional.
    float4 row[14];
    #pragma unroll
    for (int r = 0; r < 14; ++r) {
        int gr  = H0 - 3 + r;
        int grc = gr < 0 ? 0 : (gr > 255 ? 255 : gr);
        row[r] = *(const float4*)(fbase + (size_t)grc * 256 + c0);
    }

    // single latency epoch: weights (LDS) + rows (regs) drain together.
    asm volatile("s_waitcnt vmcnt(0)" ::: "memory");
    __builtin_amdgcn_sched_barrier(0);

    // ---- weights LDS -> reg: 49 conflict-free b32 (bank = wb, pair-broadcast)
    const float* ws = slab + wb;
    float wt[49];
    #pragma unroll
    for (int t = 0; t < 49; ++t) wt[t] = ws[t * 32];

    const int addrL = ((lane - 1) & 63) << 2;   // bpermute: pull from lane-1
    const int addrR = ((lane + 1) & 63) << 2;   // pull from lane+1
    const bool l0  = (lane == 0);
    const bool l63 = (lane == 63);

    float acc[8][4] = {};

    #pragma unroll
    for (int jj = 0; jj < 14; ++jj) {     // input row H0-3+jj ; out row a uses dh=jj-a
        const int gr = H0 - 3 + jj;       // wave-uniform validity
        float4 f = row[jj];
        if (gr < 0 || gr > 255) f = make_float4(0.f, 0.f, 0.f, 0.f);

        float L1 = __int_as_float(__builtin_amdgcn_ds_bpermute(addrL, __float_as_int(f.y)));
        float L2 = __int_as_float(__builtin_amdgcn_ds_bpermute(addrL, __float_as_int(f.z)));
        float L3 = __int_as_float(__builtin_amdgcn_ds_bpermute(addrL, __float_as_int(f.w)));
        float R0 = __int_as_float(__builtin_amdgcn_ds_bpermute(addrR, __float_as_int(f.x)));
        float R1 = __int_as_float(__builtin_amdgcn_ds_bpermute(addrR, __float_as_int(f.y)));
        float R2 = __int_as_float(__builtin_amdgcn_ds_bpermute(addrR, __float_as_int(f.z)));
        if (l0)  { L1 = 0.f; L2 = 0.f; L3 = 0.f; }   // cols -3..-1
        if (l63) { R0 = 0.f; R1 = 0.f; R2 = 0.f; }   // cols 256..258

        // win[k] = feat col c0 + k - 4 (k=1..10 used)
        float win[12] = {0.f, L1, L2, L3,
                         f.x, f.y, f.z, f.w,
                         R0, R1, R2, 0.f};
        #pragma unroll
        for (int a = 0; a < 8; ++a) {
            int dh = jj - a;
            if (dh >= 0 && dh <= 6) {
                #pragma unroll
                for (int dw = 0; dw < 7; ++dw) {
                    float wv = wt[dh * 7 + dw];
                    #pragma unroll
                    for (int i = 0; i < 4; ++i)
                        acc[a][i] += win[i + dw + 1] * wv;   // col c0+i+dw-3
                }
            }
        }
    }

    float* obase = out + (size_t)((n * 128 + c) * 256 + H0) * 256 + c0;
    #pragma unroll
    for (int a = 0; a < 8; ++a) {
        fx4 v = {acc[a][0], acc[a][1], acc[a][2], acc[a][3]};
        __builtin_nontemporal_store(v, (fx4*)(obase + (size_t)(a * 256)));
    }
}

extern "C" void kernel_launch(void* const* d_in, const int* in_sizes, int n_in,
                              void* d_out, int out_size, void* d_ws, size_t ws_size,
                              hipStream_t stream) {
    const float* feat = (const float*)d_in[0];
    const float* filt = (const float*)d_in[1];
    float* out = (float*)d_out;
    dim3 grid(2 * 128 * 32 / 4);          // 2048 blocks x 4 waves
    dim3 block(256);
    hipLaunchKernelGGL(block_fac_kernel, grid, block, 0, stream, feat, filt, out);
}

// Round 18
// 49.034 us; speedup vs baseline: 1.4593x; 1.2451x over previous
//
#include <hip/hip_runtime.h>
#include <stdint.h>

// Block-factorized depthwise 7x7 conv, per-(n,c,8x8-block) filters.
// feat: [N=2, C=128, H=256, W=256] f32 (NCHW)
// filters_lr: [N, C*49, 32, 32] f32 ; weight[n,hb,wb,c,t] = filt[n, c*49+t, hb, wb]
// out[n,c,h,w] = sum_t feat[n,c,h+dh-3,w+dw-3] * weight[n,h/8,w/8,c,t], t=dh*7+dw
//
// PER-WAVE SOFTWARE PIPELINE ACROSS 4 TILES (Little's-law fix).
// r9-r17 falsified: conflicts, barriers, WG slots, load epochs, write
// eviction. Invariant: 40.6us at 3.2 TB/s effective -- memory idles while
// waves compute (zero bytes in flight during the 3800cyc FMA phase).
// Here each wave owns 4 consecutive hb tiles of one (n,c). While computing
// tile t: next tile's 14 row loads (rowB regs, compiler-counted waits) and
// 7 weight global_load_lds (ping-pong LDS slab, zero VGPR) are in flight.
// Wait discipline (no manual vmcnt(0) in the loop):
//  - loop-top vmcnt(8): the 7 gld_lds are the oldest outstanding ops
//    (sched_barrier-pinned issue order); <=8 left = prev tile's stores.
//    Valid for t=0 too (prologue: Lw then Lr -> Lw oldest of 21).
//  - rowB->rowA copy at body end: compiler inserts its own counted wait.
// Rolled tile loop = one ~7.5KB body (I-cache safe). Static row buffers +
// unrolled copy (rule #20). Stores plain float4 (r17: nt perturbs codegen,
// no FETCH benefit). Grid 512 blocks x 4 waves = whole grid co-resident
// (8 waves/CU at VGPR~210, 2 blocks/CU, LDS 50KB).

#define SLABF 1568   // floats per weight slab (49 taps * 32 wb)

typedef const uint32_t __attribute__((address_space(1))) guint;
typedef uint32_t __attribute__((address_space(3))) luint;

#define STAGE_W(WT, DST)                                                        \
  do {                                                                          \
    _Pragma("unroll") for (int i_ = 0; i_ < 7; ++i_)                            \
      if (i_ < 6 || lane < 8) {                                                 \
        int f_ = (i_ << 6) | lane;                                              \
        __builtin_amdgcn_global_load_lds(                                       \
            (guint*)((WT) + (size_t)(f_ >> 3) * 1024 + (f_ & 7) * 4),           \
            (luint*)((DST) + i_ * 256), 16, 0, 0);                              \
      }                                                                         \
  } while (0)

#define LOAD_ROWS(H0v, DST)                                                     \
  do {                                                                          \
    _Pragma("unroll") for (int r_ = 0; r_ < 14; ++r_) {                         \
      int gr_  = (H0v) - 3 + r_;                                                \
      int grc_ = gr_ < 0 ? 0 : (gr_ > 255 ? 255 : gr_);                         \
      (DST)[r_] = *(const float4*)(fbase + (size_t)grc_ * 256 + c0);            \
    }                                                                           \
  } while (0)

__global__ __launch_bounds__(256, 1)
void block_fac_kernel(const float* __restrict__ feat,
                      const float* __restrict__ filt,
                      float* __restrict__ out) {
    __shared__ float s_w[4][2][SLABF];    // 50176 B: per-wave ping-pong slabs

    const int wave = threadIdx.x >> 6;
    const int lane = threadIdx.x & 63;
    const int wid  = (blockIdx.x << 2) | wave;   // 0..2047
    const int q    = wid & 7;             // hb quartet (tiles hb = 4q..4q+3)
    const int c    = (wid >> 3) & 127;
    const int n    = wid >> 10;

    const int c0 = lane << 2;             // output col base (0..252)
    const int wb = lane >> 1;             // weight block col (0..31)

    const float* fbase = feat + (size_t)(n * 128 + c) * 65536;
    const float* wtapb = filt + (size_t)((n * 128 + c) * 49) * 1024;
    float* slab0 = &s_w[wave][0][0];
    float* slab1 = &s_w[wave][1][0];

    const int addrL = ((lane - 1) & 63) << 2;   // bpermute: pull from lane-1
    const int addrR = ((lane + 1) & 63) << 2;   // pull from lane+1
    const bool l0  = (lane == 0);
    const bool l63 = (lane == 63);

    float4 rowA[14], rowB[14];

    // ---- prologue: tile 0's weights then rows (order pinned: Lw oldest)
    STAGE_W(wtapb + (q * 4 + 0) * 32, slab0);
    __builtin_amdgcn_sched_barrier(0);
    LOAD_ROWS(q * 32, rowA);
    __builtin_amdgcn_sched_barrier(0);

    #pragma unroll 1
    for (int t = 0; t < 4; ++t) {
        __builtin_amdgcn_sched_barrier(0);
        asm volatile("s_waitcnt vmcnt(8)" ::: "memory");  // slab[t&1] ready
        __builtin_amdgcn_sched_barrier(0);

        // ---- hoist this tile's weights (b32, bank = wb, pair-broadcast)
        const float* ws = (t & 1 ? slab1 : slab0) + wb;
        float wt[49];
        #pragma unroll
        for (int k = 0; k < 49; ++k) wt[k] = ws[k * 32];

        const int H0 = (q * 4 + t) * 8;   // this tile's first output row

        // ---- prefetch next tile (in flight during compute below)
        if (t < 3) {
            STAGE_W(wtapb + (q * 4 + t + 1) * 32, (t & 1 ? slab0 : slab1));
            __builtin_amdgcn_sched_barrier(0);
            LOAD_ROWS(H0 + 8, rowB);
            __builtin_amdgcn_sched_barrier(0);
        }

        // ---- compute tile t from rowA (compiler-counted waits on rowA)
        float acc[8][4] = {};
        #pragma unroll
        for (int jj = 0; jj < 14; ++jj) { // input row H0-3+jj ; out row a: dh=jj-a
            const int gr = H0 - 3 + jj;   // wave-uniform validity
            float4 f = rowA[jj];
            if (gr < 0 || gr > 255) f = make_float4(0.f, 0.f, 0.f, 0.f);

            float L1 = __int_as_float(__builtin_amdgcn_ds_bpermute(addrL, __float_as_int(f.y)));
            float L2 = __int_as_float(__builtin_amdgcn_ds_bpermute(addrL, __float_as_int(f.z)));
            float L3 = __int_as_float(__builtin_amdgcn_ds_bpermute(addrL, __float_as_int(f.w)));
            float R0 = __int_as_float(__builtin_amdgcn_ds_bpermute(addrR, __float_as_int(f.x)));
            float R1 = __int_as_float(__builtin_amdgcn_ds_bpermute(addrR, __float_as_int(f.y)));
            float R2 = __int_as_float(__builtin_amdgcn_ds_bpermute(addrR, __float_as_int(f.z)));
            if (l0)  { L1 = 0.f; L2 = 0.f; L3 = 0.f; }   // cols -3..-1
            if (l63) { R0 = 0.f; R1 = 0.f; R2 = 0.f; }   // cols 256..258

            // win[k] = feat col c0 + k - 4 (k=1..10 used)
            float win[12] = {0.f, L1, L2, L3,
                             f.x, f.y, f.z, f.w,
                             R0, R1, R2, 0.f};
            #pragma unroll
            for (int a = 0; a < 8; ++a) {
                int dh = jj - a;
                if (dh >= 0 && dh <= 6) {
                    #pragma unroll
                    for (int dw = 0; dw < 7; ++dw) {
                        float wv = wt[dh * 7 + dw];
                        #pragma unroll
                        for (int i = 0; i < 4; ++i)
                            acc[a][i] += win[i + dw + 1] * wv;   // col c0+i+dw-3
                    }
                }
            }
        }

        // ---- store tile t
        float* obase = out + (size_t)((n * 128 + c) * 256 + H0) * 256 + c0;
        #pragma unroll
        for (int a = 0; a < 8; ++a)
            *(float4*)(obase + (size_t)(a * 256)) =
                make_float4(acc[a][0], acc[a][1], acc[a][2], acc[a][3]);

        // ---- rotate row buffers (compiler inserts counted wait on rowB here)
        if (t < 3) {
            #pragma unroll
            for (int r = 0; r < 14; ++r) rowA[r] = rowB[r];
        }
    }
}

extern "C" void kernel_launch(void* const* d_in, const int* in_sizes, int n_in,
                              void* d_out, int out_size, void* d_ws, size_t ws_size,
                              hipStream_t stream) {
    const float* feat = (const float*)d_in[0];
    const float* filt = (const float*)d_in[1];
    float* out = (float*)d_out;
    dim3 grid(512);                       // 512 blocks x 4 waves x 4 tiles
    dim3 block(256);
    hipLaunchKernelGGL(block_fac_kernel, grid, block, 0, stream, feat, filt, out);
}

// Round 19
// 39.577 us; speedup vs baseline: 1.8080x; 1.2390x over previous
//
#include <hip/hip_runtime.h>
#include <stdint.h>

// Block-factorized depthwise 7x7 conv, per-(n,c,8x8-block) filters.
// feat: [N=2, C=128, H=256, W=256] f32 (NCHW)
// filters_lr: [N, C*49, 32, 32] f32 ; weight[n,hb,wb,c,t] = filt[n, c*49+t, hb, wb]
// out[n,c,h,w] = sum_t feat[n,c,h+dh-3,w+dw-3] * weight[n,h/8,w/8,c,t], t=dh*7+dw
//
// r12 vehicle (clean 40.6us: VGPR 128, zero spill, conflicts 0) with ONE
// change: the FMA loop is packed into v_pk_fma_f32 (VOP3P, 2xf32/instr).
// Clean-ensemble model: per-CU time = mem-serial (~50k cyc) + VALU-serial
// (~29k cyc) with no overlap (r9-r18 falsified every overlap/structure fix).
// Halving FMA instruction count (1568 -> 784/tile) attacks the VALU term:
// predicted -5..6us. Window pairs P1..P9 from the row float4 ({x,y},{z,w}
// free) + bpermute halo; weight splat via op_sel; accumulation order per
// element unchanged (dh-major, dw-minor) -> same absmax.

#define SLABF 1568   // floats per wave weight slab (49 taps * 32 wb)

typedef const uint32_t __attribute__((address_space(1))) guint;
typedef uint32_t __attribute__((address_space(3))) luint;
typedef float __attribute__((ext_vector_type(2))) f2;

__global__ __launch_bounds__(256, 1)
void block_fac_kernel(const float* __restrict__ feat,
                      const float* __restrict__ filt,
                      float* __restrict__ out) {
    __shared__ float s_w[4 * SLABF];      // 25088 B, one slab per wave

    const int wave = threadIdx.x >> 6;
    const int lane = threadIdx.x & 63;
    const int wid  = (blockIdx.x << 2) | wave;   // global wave id
    const int hb   = wid & 31;
    const int c    = (wid >> 5) & 127;
    const int n    = wid >> 12;

    const int c0 = lane << 2;             // output col base (0..252)
    const int wb = lane >> 1;             // weight block col (0..31)
    const int H0 = hb * 8;                // first output row

    const float* fbase = feat + (size_t)(n * 128 + c) * (256 * 256);
    const float* wtap  = filt + (size_t)((n * 128 + c) * 49) * 1024 + hb * 32;
    float* slab = s_w + wave * SLABF;

    // ---- stage the 6272B weight block into LDS: 7 fire-and-forget gathers.
    #pragma unroll
    for (int i = 0; i < 7; ++i) {
        if (i < 6 || lane < 8) {          // tail instr: only tap 48 (8 chunks)
            int f = (i << 6) | lane;
            const float* gp = wtap + (size_t)(f >> 3) * 1024 + (f & 7) * 4;
            float* lp = slab + i * 256;   // wave-uniform base; HW adds lane*16
            __builtin_amdgcn_global_load_lds((guint*)gp, (luint*)lp, 16, 0, 0);
        }
    }

    // ---- 14 input rows: own float4, clamped address -> unconditional.
    float4 row[14];
    #pragma unroll
    for (int r = 0; r < 14; ++r) {
        int gr  = H0 - 3 + r;
        int grc = gr < 0 ? 0 : (gr > 255 ? 255 : gr);
        row[r] = *(const float4*)(fbase + (size_t)grc * 256 + c0);
    }

    // single latency epoch: weights (LDS) + rows (regs) drain together.
    asm volatile("s_waitcnt vmcnt(0)" ::: "memory");
    __builtin_amdgcn_sched_barrier(0);

    // ---- weights LDS -> reg: 49 conflict-free b32 (bank = wb, pair-broadcast)
    const float* ws = slab + wb;
    float wt[49];
    #pragma unroll
    for (int t = 0; t < 49; ++t) wt[t] = ws[t * 32];

    const int addrL = ((lane - 1) & 63) << 2;   // bpermute: pull from lane-1
    const int addrR = ((lane + 1) & 63) << 2;   // pull from lane+1
    const bool l0  = (lane == 0);
    const bool l63 = (lane == 63);

    f2 acc[8][2] = {};                    // [row][col-pair], packed f32x2

    #pragma unroll
    for (int jj = 0; jj < 14; ++jj) {     // input row H0-3+jj ; out row a uses dh=jj-a
        const int gr = H0 - 3 + jj;       // wave-uniform validity
        float4 f = row[jj];
        if (gr < 0 || gr > 255) f = make_float4(0.f, 0.f, 0.f, 0.f);

        float L1 = __int_as_float(__builtin_amdgcn_ds_bpermute(addrL, __float_as_int(f.y)));
        float L2 = __int_as_float(__builtin_amdgcn_ds_bpermute(addrL, __float_as_int(f.z)));
        float L3 = __int_as_float(__builtin_amdgcn_ds_bpermute(addrL, __float_as_int(f.w)));
        float R0 = __int_as_float(__builtin_amdgcn_ds_bpermute(addrR, __float_as_int(f.x)));
        float R1 = __int_as_float(__builtin_amdgcn_ds_bpermute(addrR, __float_as_int(f.y)));
        float R2 = __int_as_float(__builtin_amdgcn_ds_bpermute(addrR, __float_as_int(f.z)));
        if (l0)  { L1 = 0.f; L2 = 0.f; L3 = 0.f; }   // cols -3..-1
        if (l63) { R0 = 0.f; R1 = 0.f; R2 = 0.f; }   // cols 256..258

        // window pairs: P[k] = {win[k], win[k+1]}, win[k] = feat col c0+k-4
        f2 P[10];
        P[1] = f2{L1,  L2};  P[2] = f2{L2,  L3};  P[3] = f2{L3,  f.x};
        P[4] = f2{f.x, f.y}; P[5] = f2{f.y, f.z}; P[6] = f2{f.z, f.w};
        P[7] = f2{f.w, R0};  P[8] = f2{R0,  R1};  P[9] = f2{R1,  R2};

        #pragma unroll
        for (int a = 0; a < 8; ++a) {
            int dh = jj - a;
            if (dh >= 0 && dh <= 6) {
                #pragma unroll
                for (int dw = 0; dw < 7; ++dw) {
                    float wv = wt[dh * 7 + dw];
                    f2 wv2 = {wv, wv};
                    acc[a][0] = __builtin_elementwise_fma(P[dw + 1], wv2, acc[a][0]);
                    acc[a][1] = __builtin_elementwise_fma(P[dw + 3], wv2, acc[a][1]);
                }
            }
        }
    }

    float* obase = out + (size_t)((n * 128 + c) * 256 + H0) * 256 + c0;
    #pragma unroll
    for (int a = 0; a < 8; ++a)
        *(float4*)(obase + (size_t)(a * 256)) =
            make_float4(acc[a][0].x, acc[a][0].y, acc[a][1].x, acc[a][1].y);
}

extern "C" void kernel_launch(void* const* d_in, const int* in_sizes, int n_in,
                              void* d_out, int out_size, void* d_ws, size_t ws_size,
                              hipStream_t stream) {
    const float* feat = (const float*)d_in[0];
    const float* filt = (const float*)d_in[1];
    float* out = (float*)d_out;
    dim3 grid(2 * 128 * 32 / 4);          // 2048 blocks x 4 waves
    dim3 block(256);
    hipLaunchKernelGGL(block_fac_kernel, grid, block, 0, stream, feat, filt, out);
}

// Round 20
// 39.184 us; speedup vs baseline: 1.8262x; 1.0100x over previous
//
#include <hip/hip_runtime.h>
#include <stdint.h>

// Block-factorized depthwise 7x7 conv, per-(n,c,8x8-block) filters.
// feat: [N=2, C=128, H=256, W=256] f32 (NCHW)
// filters_lr: [N, C*49, 32, 32] f32 ; weight[n,hb,wb,c,t] = filt[n, c*49+t, hb, wb]
// out[n,c,h,w] = sum_t feat[n,c,h+dh-3,w+dw-3] * weight[n,h/8,w/8,c,t], t=dh*7+dw
//
// r19 vehicle (best: 39.6us, VGPR 88, zero spill, conflicts 0, pk_fma) with
// ONE change: bijective XCD-aware block swizzle. Default dispatch round-robins
// consecutive blockIdx across 8 XCDs, so the 8 blocks sharing one feat
// channel (64KB) + one filt region (200KB) land on 8 DIFFERENT XCDs -> 8x L2
// feat duplication and a scattered per-XCD miss stream. Swizzle
// lbid = (bid&7)*256 + bid>>3 (nwg=2048, %8==0, bijective) puts all 8
// channel-mates on ONE XCD at the same schedule position: feat fetched once
// per L2, per-XCD live window ~1.6MB -> dense L3/DRAM access.

#define SLABF 1568   // floats per wave weight slab (49 taps * 32 wb)

typedef const uint32_t __attribute__((address_space(1))) guint;
typedef uint32_t __attribute__((address_space(3))) luint;
typedef float __attribute__((ext_vector_type(2))) f2;

__global__ __launch_bounds__(256, 1)
void block_fac_kernel(const float* __restrict__ feat,
                      const float* __restrict__ filt,
                      float* __restrict__ out) {
    __shared__ float s_w[4 * SLABF];      // 25088 B, one slab per wave

    const int wave = threadIdx.x >> 6;
    const int lane = threadIdx.x & 63;
    // XCD swizzle: blocks b with b%8==j (-> XCD j) get contiguous logical ids
    const int lbid = ((blockIdx.x & 7) << 8) | (blockIdx.x >> 3);
    const int wid  = (lbid << 2) | wave;  // global wave id
    const int hb   = wid & 31;
    const int c    = (wid >> 5) & 127;
    const int n    = wid >> 12;

    const int c0 = lane << 2;             // output col base (0..252)
    const int wb = lane >> 1;             // weight block col (0..31)
    const int H0 = hb * 8;                // first output row

    const float* fbase = feat + (size_t)(n * 128 + c) * (256 * 256);
    const float* wtap  = filt + (size_t)((n * 128 + c) * 49) * 1024 + hb * 32;
    float* slab = s_w + wave * SLABF;

    // ---- stage the 6272B weight block into LDS: 7 fire-and-forget gathers.
    #pragma unroll
    for (int i = 0; i < 7; ++i) {
        if (i < 6 || lane < 8) {          // tail instr: only tap 48 (8 chunks)
            int f = (i << 6) | lane;
            const float* gp = wtap + (size_t)(f >> 3) * 1024 + (f & 7) * 4;
            float* lp = slab + i * 256;   // wave-uniform base; HW adds lane*16
            __builtin_amdgcn_global_load_lds((guint*)gp, (luint*)lp, 16, 0, 0);
        }
    }

    // ---- 14 input rows: own float4, clamped address -> unconditional.
    float4 row[14];
    #pragma unroll
    for (int r = 0; r < 14; ++r) {
        int gr  = H0 - 3 + r;
        int grc = gr < 0 ? 0 : (gr > 255 ? 255 : gr);
        row[r] = *(const float4*)(fbase + (size_t)grc * 256 + c0);
    }

    // single latency epoch: weights (LDS) + rows (regs) drain together.
    asm volatile("s_waitcnt vmcnt(0)" ::: "memory");
    __builtin_amdgcn_sched_barrier(0);

    // ---- weights LDS -> reg: 49 conflict-free b32 (bank = wb, pair-broadcast)
    const float* ws = slab + wb;
    float wt[49];
    #pragma unroll
    for (int t = 0; t < 49; ++t) wt[t] = ws[t * 32];

    const int addrL = ((lane - 1) & 63) << 2;   // bpermute: pull from lane-1
    const int addrR = ((lane + 1) & 63) << 2;   // pull from lane+1
    const bool l0  = (lane == 0);
    const bool l63 = (lane == 63);

    f2 acc[8][2] = {};                    // [row][col-pair], packed f32x2

    #pragma unroll
    for (int jj = 0; jj < 14; ++jj) {     // input row H0-3+jj ; out row a uses dh=jj-a
        const int gr = H0 - 3 + jj;       // wave-uniform validity
        float4 f = row[jj];
        if (gr < 0 || gr > 255) f = make_float4(0.f, 0.f, 0.f, 0.f);

        float L1 = __int_as_float(__builtin_amdgcn_ds_bpermute(addrL, __float_as_int(f.y)));
        float L2 = __int_as_float(__builtin_amdgcn_ds_bpermute(addrL, __float_as_int(f.z)));
        float L3 = __int_as_float(__builtin_amdgcn_ds_bpermute(addrL, __float_as_int(f.w)));
        float R0 = __int_as_float(__builtin_amdgcn_ds_bpermute(addrR, __float_as_int(f.x)));
        float R1 = __int_as_float(__builtin_amdgcn_ds_bpermute(addrR, __float_as_int(f.y)));
        float R2 = __int_as_float(__builtin_amdgcn_ds_bpermute(addrR, __float_as_int(f.z)));
        if (l0)  { L1 = 0.f; L2 = 0.f; L3 = 0.f; }   // cols -3..-1
        if (l63) { R0 = 0.f; R1 = 0.f; R2 = 0.f; }   // cols 256..258

        // window pairs: P[k] = {win[k], win[k+1]}, win[k] = feat col c0+k-4
        f2 P[10];
        P[1] = f2{L1,  L2};  P[2] = f2{L2,  L3};  P[3] = f2{L3,  f.x};
        P[4] = f2{f.x, f.y}; P[5] = f2{f.y, f.z}; P[6] = f2{f.z, f.w};
        P[7] = f2{f.w, R0};  P[8] = f2{R0,  R1};  P[9] = f2{R1,  R2};

        #pragma unroll
        for (int a = 0; a < 8; ++a) {
            int dh = jj - a;
            if (dh >= 0 && dh <= 6) {
                #pragma unroll
                for (int dw = 0; dw < 7; ++dw) {
                    float wv = wt[dh * 7 + dw];
                    f2 wv2 = {wv, wv};
                    acc[a][0] = __builtin_elementwise_fma(P[dw + 1], wv2, acc[a][0]);
                    acc[a][1] = __builtin_elementwise_fma(P[dw + 3], wv2, acc[a][1]);
                }
            }
        }
    }

    float* obase = out + (size_t)((n * 128 + c) * 256 + H0) * 256 + c0;
    #pragma unroll
    for (int a = 0; a < 8; ++a)
        *(float4*)(obase + (size_t)(a * 256)) =
            make_float4(acc[a][0].x, acc[a][0].y, acc[a][1].x, acc[a][1].y);
}

extern "C" void kernel_launch(void* const* d_in, const int* in_sizes, int n_in,
                              void* d_out, int out_size, void* d_ws, size_t ws_size,
                              hipStream_t stream) {
    const float* feat = (const float*)d_in[0];
    const float* filt = (const float*)d_in[1];
    float* out = (float*)d_out;
    dim3 grid(2 * 128 * 32 / 4);          // 2048 blocks x 4 waves
    dim3 block(256);
    hipLaunchKernelGGL(block_fac_kernel, grid, block, 0, stream, feat, filt, out);
}